// Round 4
// baseline (327.588 us; speedup 1.0000x reference)
//
#include <hip/hip_runtime.h>
#include <math.h>

typedef _Float16 f16x8 __attribute__((ext_vector_type(8)));
typedef _Float16 f16x4 __attribute__((ext_vector_type(4)));
typedef float f32x4 __attribute__((ext_vector_type(4)));

__device__ __forceinline__ void async_copy16(const void* g, void* l) {
    __builtin_amdgcn_global_load_lds(
        (const __attribute__((address_space(1))) void*)g,
        (__attribute__((address_space(3))) void*)l, 16, 0, 0);
}

// ---------------- cast x (fp32) -> f16 ----------------
__global__ __launch_bounds__(256) void cast_f32_f16_kernel(
    const float4* __restrict__ in, f16x4* __restrict__ out) {
    int i = blockIdx.x * 256 + threadIdx.x;
    float4 v = in[i];
    f16x4 o;
    o[0] = (_Float16)v.x; o[1] = (_Float16)v.y;
    o[2] = (_Float16)v.z; o[3] = (_Float16)v.w;
    out[i] = o;
}

// ---------------- fused TT-core -> dense weight builds ----------------
__global__ __launch_bounds__(256) void build_W0t_fused(
    const float* __restrict__ c0a, const float* __restrict__ c0b,
    const float* __restrict__ c0c, _Float16* __restrict__ W0t) {
    __shared__ float G[16384];  // [q16][r8][j16][k8]
    const int o = blockIdx.x >> 4, p = blockIdx.x & 15;
    const int t = threadIdx.x;
#pragma unroll
    for (int n = 0; n < 64; ++n) {
        int idx = t + 256 * n;
        int k = idx & 7, j = (idx >> 3) & 15, r = (idx >> 7) & 7, q = idx >> 10;
        float s = 0.f;
#pragma unroll
        for (int ss = 0; ss < 8; ++ss)
            s += c0b[((r * 16 + j) * 16 + p) * 8 + ss] * c0c[(ss * 8 + k) * 16 + q];
        G[idx] = s;
    }
    __syncthreads();
    const int i = t >> 5, j = (t >> 1) & 15, kq = t & 1;
    float a[8];
#pragma unroll
    for (int r = 0; r < 8; ++r) a[r] = c0a[(i * 16 + o) * 8 + r];
    const float4* G4 = (const float4*)G;
#pragma unroll
    for (int q = 0; q < 16; ++q) {
        float4 acc = {0.f, 0.f, 0.f, 0.f};
#pragma unroll
        for (int r = 0; r < 8; ++r) {
            float4 g = G4[q * 256 + r * 32 + j * 2 + kq];
            acc.x += a[r] * g.x; acc.y += a[r] * g.y;
            acc.z += a[r] * g.z; acc.w += a[r] * g.w;
        }
        f16x4 h4;
        h4[0] = (_Float16)acc.x; h4[1] = (_Float16)acc.y;
        h4[2] = (_Float16)acc.z; h4[3] = (_Float16)acc.w;
        *(f16x4*)(W0t + (size_t)((o * 16 + p) * 16 + q) * 1024 + t * 4) = h4;
    }
}

__global__ __launch_bounds__(256) void build_W1t_fused(
    const float* __restrict__ c1a, const float* __restrict__ c1b,
    const float* __restrict__ c1c, _Float16* __restrict__ W1t) {
    __shared__ float G[16384];  // [q8][r8][j16][k16]
    const int o = blockIdx.x >> 4, p = blockIdx.x & 15;
    const int t = threadIdx.x;
#pragma unroll
    for (int n = 0; n < 64; ++n) {
        int idx = t + 256 * n;
        int k = idx & 15, j = (idx >> 4) & 15, r = (idx >> 8) & 7, q = idx >> 11;
        float s = 0.f;
#pragma unroll
        for (int ss = 0; ss < 8; ++ss)
            s += c1b[((r * 16 + j) * 16 + p) * 8 + ss] * c1c[(ss * 16 + k) * 8 + q];
        G[idx] = s;
    }
    __syncthreads();
    const int ig = t >> 6, j = (t >> 2) & 15, kq = t & 3;
    float a[4][8];
#pragma unroll
    for (int ii = 0; ii < 4; ++ii)
#pragma unroll
        for (int r = 0; r < 8; ++r) a[ii][r] = c1a[((ig * 4 + ii) * 8 + o) * 8 + r];
    const float4* G4 = (const float4*)G;
#pragma unroll
    for (int q = 0; q < 8; ++q) {
        float4 acc[4] = {{0,0,0,0},{0,0,0,0},{0,0,0,0},{0,0,0,0}};
#pragma unroll
        for (int r = 0; r < 8; ++r) {
            float4 g = G4[q * 512 + r * 64 + j * 4 + kq];
#pragma unroll
            for (int ii = 0; ii < 4; ++ii) {
                acc[ii].x += a[ii][r] * g.x; acc[ii].y += a[ii][r] * g.y;
                acc[ii].z += a[ii][r] * g.z; acc[ii].w += a[ii][r] * g.w;
            }
        }
        const size_t rowbase = (size_t)((o * 16 + p) * 8 + q) * 4096;
#pragma unroll
        for (int ii = 0; ii < 4; ++ii) {
            f16x4 h4;
            h4[0] = (_Float16)acc[ii].x; h4[1] = (_Float16)acc[ii].y;
            h4[2] = (_Float16)acc[ii].z; h4[3] = (_Float16)acc[ii].w;
            *(f16x4*)(W1t + rowbase + (ig * 4 + ii) * 256 + j * 16 + kq * 4) = h4;
        }
    }
}

// ---------------- GEMM: C = A(MxK) * Bt(NxK)^T, BK=64 ----------------
// LDS swizzle: slot c of row rho holds k-chunk (c ^ (rho&7)); staging stays
// linear lane*16 (global_load_lds constraint), reads are 2-way (free).
// OUTMODE 1: f16 C0 = gelu(acc + bias)                     (GEMM1)
// OUTMODE 3: z==0 -> fp32 C0 = acc + bias; z==1 -> f16 C1 = acc  (GEMM2 split-K)
template <int OUTMODE>
__global__ __launch_bounds__(256) void gemm_bt64_kernel(
    const _Float16* __restrict__ A, const _Float16* __restrict__ Bt,
    const float* __restrict__ bias, void* __restrict__ C0, void* __restrict__ C1,
    int M, int N, int K, int klen) {
    constexpr int BK = 64;
    __shared__ alignas(16) _Float16 sA[128 * BK];
    __shared__ alignas(16) _Float16 sB[128 * BK];

    const int t = threadIdx.x, lane = t & 63, w = t >> 6;
    const int m0 = blockIdx.x * 128, n0 = blockIdx.y * 128;
    const int kbeg = blockIdx.z * klen;
    const int wm = (w & 1) * 64, wn = (w >> 1) * 64;
    const int lm = lane & 15, lq = lane >> 4;

    f32x4 acc[4][4] = {};

    // staging: slot s = w*256 + m*64 + lane; row = s>>3; cslot = s&7
    const int s0 = w * 256 + lane;
    const int row0 = s0 >> 3;                    // issues m add 8*m rows
    const int cslot = s0 & 7;
    const int kofs = (cslot ^ (row0 & 7)) * 8;   // swizzled source k-chunk
    const _Float16* gA = A + (size_t)(m0 + row0) * K + kbeg + kofs;
    const _Float16* gB = Bt + (size_t)(n0 + row0) * K + kbeg + kofs;
    _Float16* lA = sA + s0 * 8;                  // wave base + lane*16B, linear
    _Float16* lB = sB + s0 * 8;
    const size_t rs = (size_t)8 * K;             // 8-row stride between issues

    for (int k0 = 0; k0 < klen; k0 += BK) {
#pragma unroll
        for (int m = 0; m < 4; ++m) {
            async_copy16(gA + k0 + m * rs, lA + m * 512);
            async_copy16(gB + k0 + m * rs, lB + m * 512);
        }
        __syncthreads();
#pragma unroll
        for (int kk = 0; kk < 2; ++kk) {
            f16x8 af[4], bf[4];
            const int ks = ((kk * 4 + lq) ^ (lm & 7)) * 8;
#pragma unroll
            for (int i = 0; i < 4; ++i) {
                af[i] = *(const f16x8*)(sA + (wm + i * 16 + lm) * BK + ks);
                bf[i] = *(const f16x8*)(sB + (wn + i * 16 + lm) * BK + ks);
            }
#pragma unroll
            for (int i = 0; i < 4; ++i)
#pragma unroll
                for (int j = 0; j < 4; ++j)
                    acc[i][j] = __builtin_amdgcn_mfma_f32_16x16x32_f16(af[i], bf[j], acc[i][j], 0, 0, 0);
        }
        __syncthreads();
    }

    if (OUTMODE == 1) {
        _Float16* C = (_Float16*)C0;
#pragma unroll
        for (int i = 0; i < 4; ++i)
#pragma unroll
            for (int j = 0; j < 4; ++j) {
                int col = n0 + wn + j * 16 + lm;
                float bv = bias[col];
#pragma unroll
                for (int r = 0; r < 4; ++r) {
                    int row = m0 + wm + i * 16 + lq * 4 + r;
                    float v = acc[i][j][r] + bv;
                    float uu = v * (0.7978845608028654f + 0.0356774081363001f * v * v);
                    float e = __builtin_amdgcn_exp2f(uu * 2.8853900817779268f);
                    float rc = __builtin_amdgcn_rcpf(e + 1.0f);
                    C[(size_t)row * N + col] = (_Float16)(v * (1.0f - rc));
                }
            }
    } else {  // OUTMODE 3
        if (blockIdx.z == 0) {
            float* C = (float*)C0;
#pragma unroll
            for (int i = 0; i < 4; ++i)
#pragma unroll
                for (int j = 0; j < 4; ++j) {
                    int col = n0 + wn + j * 16 + lm;
                    float bv = bias[col];
#pragma unroll
                    for (int r = 0; r < 4; ++r) {
                        int row = m0 + wm + i * 16 + lq * 4 + r;
                        C[(size_t)row * N + col] = acc[i][j][r] + bv;
                    }
                }
        } else {
            _Float16* C = (_Float16*)C1;
#pragma unroll
            for (int i = 0; i < 4; ++i)
#pragma unroll
                for (int j = 0; j < 4; ++j) {
                    int col = n0 + wn + j * 16 + lm;
#pragma unroll
                    for (int r = 0; r < 4; ++r) {
                        int row = m0 + wm + i * 16 + lq * 4 + r;
                        C[(size_t)row * N + col] = (_Float16)acc[i][j][r];
                    }
                }
        }
    }
}

// out += (float)p1, vectorized x4
__global__ __launch_bounds__(256) void reduce_add_kernel(
    float4* __restrict__ out, const f16x4* __restrict__ p1) {
    int i = blockIdx.x * 256 + threadIdx.x;
    float4 o = out[i];
    f16x4 p = p1[i];
    o.x += (float)p[0]; o.y += (float)p[1];
    o.z += (float)p[2]; o.w += (float)p[3];
    out[i] = o;
}

extern "C" void kernel_launch(void* const* d_in, const int* in_sizes, int n_in,
                              void* d_out, int out_size, void* d_ws, size_t ws_size,
                              hipStream_t stream) {
    const float* x   = (const float*)d_in[0];
    const float* c0a = (const float*)d_in[1];
    const float* c0b = (const float*)d_in[2];
    const float* c0c = (const float*)d_in[3];
    const float* b0  = (const float*)d_in[4];
    const float* c1a = (const float*)d_in[5];
    const float* c1b = (const float*)d_in[6];
    const float* c1c = (const float*)d_in[7];
    const float* b1  = (const float*)d_in[8];
    float* out = (float*)d_out;

    char* ws = (char*)d_ws;
    _Float16* xh  = (_Float16*)(ws);                          // 16 MB (dead after GEMM1)
    _Float16* W0t = (_Float16*)(ws + (size_t)(16u << 20));    //  8 MB
    _Float16* W1t = (_Float16*)(ws + (size_t)(24u << 20));    //  8 MB
    _Float16* h   = (_Float16*)(ws + (size_t)(32u << 20));    // 64 MB
    _Float16* p1  = (_Float16*)(ws);                          // 16 MB, overlays dead xh

    // 1) cast x -> f16
    cast_f32_f16_kernel<<<dim3(8192), dim3(256), 0, stream>>>((const float4*)x, (f16x4*)xh);
    // 2) TT cores -> dense transposed weights (N x K, f16)
    build_W0t_fused<<<dim3(256), dim3(256), 0, stream>>>(c0a, c0b, c0c, W0t);
    build_W1t_fused<<<dim3(128), dim3(256), 0, stream>>>(c1a, c1b, c1c, W1t);
    // 3) h = gelu(x @ W0 + b0)   M=8192 N=4096 K=1024
    gemm_bt64_kernel<1><<<dim3(64, 32, 1), dim3(256), 0, stream>>>(
        xh, W0t, b0, (void*)h, nullptr, 8192, 4096, 1024, 1024);
    // 4) out = h @ W1 + b1, split-K=2 in ONE dispatch (4 blocks/CU)
    gemm_bt64_kernel<3><<<dim3(64, 8, 2), dim3(256), 0, stream>>>(
        h, W1t, b1, (void*)out, (void*)p1, 8192, 1024, 4096, 2048);
    // 5) out += p1
    reduce_add_kernel<<<dim3(8192), dim3(256), 0, stream>>>((float4*)out, (const f16x4*)p1);
}

// Round 5
// 306.021 us; speedup vs baseline: 1.0705x; 1.0705x over previous
//
#include <hip/hip_runtime.h>
#include <math.h>

typedef _Float16 f16x8 __attribute__((ext_vector_type(8)));
typedef _Float16 f16x4 __attribute__((ext_vector_type(4)));
typedef float f32x16 __attribute__((ext_vector_type(16)));

__device__ __forceinline__ void async_copy16(const void* g, void* l) {
    __builtin_amdgcn_global_load_lds(
        (const __attribute__((address_space(1))) void*)g,
        (__attribute__((address_space(3))) void*)l, 16, 0, 0);
}

// ---------------- fused prep: cast x->f16 | build W0t | build W1t ----------------
// blocks 0..1023   : cast (8 float4 / thread)
// blocks 1024..1279: W0t build (o,p) = b-1024
// blocks 1280..1407: W1t build (o,p) = b-1280
__global__ __launch_bounds__(256) void prep_kernel(
    const float* __restrict__ x, _Float16* __restrict__ xh,
    const float* __restrict__ c0a, const float* __restrict__ c0b,
    const float* __restrict__ c0c, _Float16* __restrict__ W0t,
    const float* __restrict__ c1a, const float* __restrict__ c1b,
    const float* __restrict__ c1c, _Float16* __restrict__ W1t) {
    __shared__ float G[16384];
    const int b = blockIdx.x, t = threadIdx.x;
    if (b < 1024) {
        const float4* in4 = (const float4*)x;
        f16x4* out4 = (f16x4*)xh;
        const int base = b * 2048 + t;
#pragma unroll
        for (int u = 0; u < 8; ++u) {
            float4 v = in4[base + u * 256];
            f16x4 o;
            o[0] = (_Float16)v.x; o[1] = (_Float16)v.y;
            o[2] = (_Float16)v.z; o[3] = (_Float16)v.w;
            out4[base + u * 256] = o;
        }
    } else if (b < 1280) {
        const int o = (b - 1024) >> 4, p = (b - 1024) & 15;
        // G[q16][r8][j16][k8] = sum_s c0b[r,j,p,s]*c0c[s,k,q]
#pragma unroll
        for (int n = 0; n < 64; ++n) {
            int idx = t + 256 * n;
            int k = idx & 7, j = (idx >> 3) & 15, r = (idx >> 7) & 7, q = idx >> 10;
            float s = 0.f;
#pragma unroll
            for (int ss = 0; ss < 8; ++ss)
                s += c0b[((r * 16 + j) * 16 + p) * 8 + ss] * c0c[(ss * 8 + k) * 16 + q];
            G[idx] = s;
        }
        __syncthreads();
        const int i = t >> 5, j = (t >> 1) & 15, kq = t & 1;
        float a[8];
#pragma unroll
        for (int r = 0; r < 8; ++r) a[r] = c0a[(i * 16 + o) * 8 + r];
        const float4* G4 = (const float4*)G;
#pragma unroll
        for (int q = 0; q < 16; ++q) {
            float4 acc = {0.f, 0.f, 0.f, 0.f};
#pragma unroll
            for (int r = 0; r < 8; ++r) {
                float4 g = G4[q * 256 + r * 32 + j * 2 + kq];
                acc.x += a[r] * g.x; acc.y += a[r] * g.y;
                acc.z += a[r] * g.z; acc.w += a[r] * g.w;
            }
            f16x4 h4;
            h4[0] = (_Float16)acc.x; h4[1] = (_Float16)acc.y;
            h4[2] = (_Float16)acc.z; h4[3] = (_Float16)acc.w;
            *(f16x4*)(W0t + (size_t)((o * 16 + p) * 16 + q) * 1024 + t * 4) = h4;
        }
    } else {
        const int o = (b - 1280) >> 4, p = (b - 1280) & 15;
        // G[q8][r8][j16][k16] = sum_s c1b[r,j,p,s]*c1c[s,k,q]
#pragma unroll
        for (int n = 0; n < 64; ++n) {
            int idx = t + 256 * n;
            int k = idx & 15, j = (idx >> 4) & 15, r = (idx >> 8) & 7, q = idx >> 11;
            float s = 0.f;
#pragma unroll
            for (int ss = 0; ss < 8; ++ss)
                s += c1b[((r * 16 + j) * 16 + p) * 8 + ss] * c1c[(ss * 16 + k) * 8 + q];
            G[idx] = s;
        }
        __syncthreads();
        const int ig = t >> 6, j = (t >> 2) & 15, kq = t & 3;
        float a[4][8];
#pragma unroll
        for (int ii = 0; ii < 4; ++ii)
#pragma unroll
            for (int r = 0; r < 8; ++r) a[ii][r] = c1a[((ig * 4 + ii) * 8 + o) * 8 + r];
        const float4* G4 = (const float4*)G;
#pragma unroll
        for (int q = 0; q < 8; ++q) {
            float4 acc[4] = {{0,0,0,0},{0,0,0,0},{0,0,0,0},{0,0,0,0}};
#pragma unroll
            for (int r = 0; r < 8; ++r) {
                float4 g = G4[q * 512 + r * 64 + j * 4 + kq];
#pragma unroll
                for (int ii = 0; ii < 4; ++ii) {
                    acc[ii].x += a[ii][r] * g.x; acc[ii].y += a[ii][r] * g.y;
                    acc[ii].z += a[ii][r] * g.z; acc[ii].w += a[ii][r] * g.w;
                }
            }
            const size_t rowbase = (size_t)((o * 16 + p) * 8 + q) * 4096;
#pragma unroll
            for (int ii = 0; ii < 4; ++ii) {
                f16x4 h4;
                h4[0] = (_Float16)acc[ii].x; h4[1] = (_Float16)acc[ii].y;
                h4[2] = (_Float16)acc[ii].z; h4[3] = (_Float16)acc[ii].w;
                *(f16x4*)(W1t + rowbase + (ig * 4 + ii) * 256 + j * 16 + kq * 4) = h4;
            }
        }
    }
}

// ---------------- GEMM: C = A(MxK) * Bt(NxK)^T, BK=64, 32x32x16 MFMA ----------------
// LDS: slot c of row rho holds k-chunk (c ^ (rho&7)); staging linear lane*16.
// Wave tile 64x64 = 2x2 of 32x32. A-frag: m=lane&31, k=(lane>>5)*8+j.
// C/D: col=lane&31, row=(reg&3)+8*(reg>>2)+4*(lane>>5).
// OUTMODE 1: f16 C = gelu(acc+bias);  OUTMODE 0: fp32 C = acc+bias
template <int OUTMODE>
__global__ __launch_bounds__(256) void gemm32_kernel(
    const _Float16* __restrict__ A, const _Float16* __restrict__ Bt,
    const float* __restrict__ bias, void* __restrict__ Cout,
    int M, int N, int K) {
    constexpr int BK = 64;
    __shared__ alignas(16) _Float16 sA[128 * BK];
    __shared__ alignas(16) _Float16 sB[128 * BK];

    const int t = threadIdx.x, lane = t & 63, w = t >> 6;
    const int m0 = blockIdx.x * 128, n0 = blockIdx.y * 128;
    const int wm = (w & 1) * 64, wn = (w >> 1) * 64;
    const int l31 = lane & 31, lh = lane >> 5;

    f32x16 acc[2][2] = {};

    // staging (same as R4): slot s0 = w*256+lane; row=s0>>3; cslot=s0&7
    const int s0 = w * 256 + lane;
    const int row0 = s0 >> 3;
    const int cslot = s0 & 7;
    const int kofs = (cslot ^ (row0 & 7)) * 8;
    const _Float16* gA = A + (size_t)(m0 + row0) * K + kofs;
    const _Float16* gB = Bt + (size_t)(n0 + row0) * K + kofs;
    _Float16* lA = sA + s0 * 8;
    _Float16* lB = sB + s0 * 8;
    const size_t rs = (size_t)8 * K;

    for (int k0 = 0; k0 < K; k0 += BK) {
#pragma unroll
        for (int m = 0; m < 4; ++m) {
            async_copy16(gA + k0 + m * rs, lA + m * 512);
            async_copy16(gB + k0 + m * rs, lB + m * 512);
        }
        __syncthreads();
#pragma unroll
        for (int kk = 0; kk < 4; ++kk) {
            f16x8 af[2], bf[2];
            const int c = kk * 2 + lh;           // global k-chunk within BK
            const int sl = (c ^ (l31 & 7)) * 8;  // swizzled slot offset (elements)
#pragma unroll
            for (int i = 0; i < 2; ++i) {
                af[i] = *(const f16x8*)(sA + (wm + i * 32 + l31) * BK + sl);
                bf[i] = *(const f16x8*)(sB + (wn + i * 32 + l31) * BK + sl);
            }
#pragma unroll
            for (int i = 0; i < 2; ++i)
#pragma unroll
                for (int j = 0; j < 2; ++j)
                    acc[i][j] = __builtin_amdgcn_mfma_f32_32x32x16_f16(af[i], bf[j], acc[i][j], 0, 0, 0);
        }
        __syncthreads();
    }

#pragma unroll
    for (int i = 0; i < 2; ++i)
#pragma unroll
        for (int j = 0; j < 2; ++j) {
            const int col = n0 + wn + j * 32 + l31;
            const float bv = bias[col];
            const int rbase = m0 + wm + i * 32 + 4 * lh;
            if (OUTMODE == 1) {
                _Float16* C = (_Float16*)Cout;
#pragma unroll
                for (int r = 0; r < 16; ++r) {
                    int row = rbase + (r & 3) + 8 * (r >> 2);
                    float v = acc[i][j][r] + bv;
                    float uu = v * (0.7978845608028654f + 0.0356774081363001f * v * v);
                    float e = __builtin_amdgcn_exp2f(uu * 2.8853900817779268f);
                    float rc = __builtin_amdgcn_rcpf(e + 1.0f);
                    C[(size_t)row * N + col] = (_Float16)(v * (1.0f - rc));
                }
            } else {
                float* C = (float*)Cout;
#pragma unroll
                for (int r = 0; r < 16; ++r) {
                    int row = rbase + (r & 3) + 8 * (r >> 2);
                    C[(size_t)row * N + col] = acc[i][j][r] + bv;
                }
            }
        }
}

extern "C" void kernel_launch(void* const* d_in, const int* in_sizes, int n_in,
                              void* d_out, int out_size, void* d_ws, size_t ws_size,
                              hipStream_t stream) {
    const float* x   = (const float*)d_in[0];
    const float* c0a = (const float*)d_in[1];
    const float* c0b = (const float*)d_in[2];
    const float* c0c = (const float*)d_in[3];
    const float* b0  = (const float*)d_in[4];
    const float* c1a = (const float*)d_in[5];
    const float* c1b = (const float*)d_in[6];
    const float* c1c = (const float*)d_in[7];
    const float* b1  = (const float*)d_in[8];
    float* out = (float*)d_out;

    char* ws = (char*)d_ws;
    _Float16* xh  = (_Float16*)(ws);                          // 16 MB
    _Float16* W0t = (_Float16*)(ws + (size_t)(16u << 20));    //  8 MB
    _Float16* W1t = (_Float16*)(ws + (size_t)(24u << 20));    //  8 MB
    _Float16* h   = (_Float16*)(ws + (size_t)(32u << 20));    // 64 MB

    // 1) fused prep: cast + both weight builds (1408 blocks)
    prep_kernel<<<dim3(1408), dim3(256), 0, stream>>>(
        x, xh, c0a, c0b, c0c, W0t, c1a, c1b, c1c, W1t);
    // 2) h = gelu(x @ W0 + b0)   M=8192 N=4096 K=1024
    gemm32_kernel<1><<<dim3(64, 32), dim3(256), 0, stream>>>(
        xh, W0t, b0, (void*)h, 8192, 4096, 1024);
    // 3) out = h @ W1 + b1       M=8192 N=1024 K=4096
    gemm32_kernel<0><<<dim3(64, 8), dim3(256), 0, stream>>>(
        h, W1t, b1, (void*)out, 8192, 1024, 4096);
}